// Round 12
// baseline (157.568 us; speedup 1.0000x reference)
//
#include <hip/hip_runtime.h>
#include <hip/hip_bf16.h>
#include <cstdint>
#include <cstddef>

// ---------------- types / helpers ----------------
typedef float  f32x4  __attribute__((ext_vector_type(4)));
typedef __bf16 bf16x8 __attribute__((ext_vector_type(8)));
typedef unsigned short u16x8 __attribute__((ext_vector_type(8)));

__device__ __forceinline__ unsigned short f2bf(float f) {
    unsigned u = __float_as_uint(f);
    u += 0x7FFFu + ((u >> 16) & 1u);   // round-to-nearest-even
    return (unsigned short)(u >> 16);
}

// ---------------- problem constants ----------------
// B=64, C=80, IN_CH=300, J=8192, S=8, OUT=1024
// feature [64,2048,14,14] (131072 rows of 196), out [64,80]

// ---------------- ws layout (bytes) ----------------
constexpr size_t OFF_FEATB = 0;          // 64*2048 bf16  = 262144
constexpr size_t OFF_X2B   = 262144;     // 80*1024 bf16  = 163840
constexpr size_t OFF_XB    = 425984;     // 80*2048 bf16  = 327680
constexpr size_t OFF_IMG   = 753664;     // 64*8192 f32   = 2097152
constexpr size_t OFF_CLS   = 2850816;    // 80*8192 f32   = 2621440
constexpr size_t OFF_G     = 5472256;    // 80*8192 f32   = 2621440

// =================== D1 roles (256 threads) ===================

// maxpool r11: 8 lanes/row, 8 rows/wave, 32 rows/block, 4096 blocks.
// 7 INDEPENDENT named loads per thread (no outer loop the compiler can
// pipeline-break) -> 7 loads in flight per lane. fmax idempotent: all lanes
// also read the row tail p[48] (broadcast).
__device__ __forceinline__ void maxpool_role(int vbid, const float* __restrict__ feature,
                                             unsigned short* __restrict__ featb) {
    int wave = threadIdx.x >> 6, lane = threadIdx.x & 63;
    int r = lane >> 3, q = lane & 7;
    int row = vbid * 32 + wave * 8 + r;
    const float4* p = (const float4*)(feature + (size_t)row * 196);
    float4 v0 = p[q];
    float4 v1 = p[q + 8];
    float4 v2 = p[q + 16];
    float4 v3 = p[q + 24];
    float4 v4 = p[q + 32];
    float4 v5 = p[q + 40];
    float4 v6 = p[48];
    float m0 = fmaxf(fmaxf(v0.x, v0.y), fmaxf(v0.z, v0.w));
    float m1 = fmaxf(fmaxf(v1.x, v1.y), fmaxf(v1.z, v1.w));
    float m2 = fmaxf(fmaxf(v2.x, v2.y), fmaxf(v2.z, v2.w));
    float m3 = fmaxf(fmaxf(v3.x, v3.y), fmaxf(v3.z, v3.w));
    float m4 = fmaxf(fmaxf(v4.x, v4.y), fmaxf(v4.z, v4.w));
    float m5 = fmaxf(fmaxf(v5.x, v5.y), fmaxf(v5.z, v5.w));
    float m6 = fmaxf(fmaxf(v6.x, v6.y), fmaxf(v6.z, v6.w));
    float m = fmaxf(fmaxf(fmaxf(m0, m1), fmaxf(m2, m3)), fmaxf(fmaxf(m4, m5), m6));
    #pragma unroll
    for (int off = 1; off < 8; off <<= 1) m = fmaxf(m, __shfl_xor(m, off));
    if (q == 0) featb[row] = f2bf(m);
}

// GCN front r11 (LDS-lean): no adj matrix in LDS. Using
//   x_next[c] = dinv[c] * sum_e A[e,c] * (dinv[e] * x[e])
// A (25.6 KB) stays L1-resident; LDS holds only dinv + scaled vectors (5.4 KB)
// so maxpool blocks in the same kernel are not LDS-starved (round 10: 31 KB
// LDS -> 5 blocks/CU cap).
// Block owns 8 j-columns (j0 = idx*8); thread (j = t&7, slot = t>>3) owns
// c = {slot, slot+32, slot+64(<80)}.
__device__ __forceinline__ void gcn_front_role(int idx, const float* __restrict__ inp,
                                               const float* __restrict__ W1,
                                               const float* __restrict__ A,
                                               unsigned short* __restrict__ x2b,
                                               float* smem) {
    float* dinv = smem;            // [80]
    float* ys   = smem + 80;       // [80][8]  dinv[e]*y0[e][j]
    float* xs   = smem + 720;      // [80][8]  dinv[e]*x1[e][j]
    int t = threadIdx.x;
    int j = t & 7, slot = t >> 3;                 // slot 0..31
    int j0 = idx * 8;
    int c0 = slot, c1 = slot + 32, c2 = slot + 64;
    bool has3 = (slot < 16);                      // wave-uniform

    if (t < 80) {
        const float4* ar = (const float4*)(A + t * 80);
        float4 s4 = {0.f, 0.f, 0.f, 0.f};
        #pragma unroll
        for (int q = 0; q < 20; q++) {
            float4 v = ar[q];
            s4.x += v.x; s4.y += v.y; s4.z += v.z; s4.w += v.w;
        }
        dinv[t] = 1.0f / sqrtf(s4.x + s4.y + s4.z + s4.w);
    }

    // y0: 300 serial k, W1 column loads batched 4-deep for MLP
    const float* wcol = W1 + j0 + j;
    const float* i0 = inp + c0 * 300;
    const float* i1 = inp + c1 * 300;
    const float* i2 = inp + c2 * 300;
    float a0 = 0.f, a1 = 0.f, a2 = 0.f;
    for (int k = 0; k < 300; k += 4) {
        float w[4], p0[4], p1[4], p2[4];
        #pragma unroll
        for (int u = 0; u < 4; u++) w[u] = wcol[(size_t)(k + u) * 1024];
        #pragma unroll
        for (int u = 0; u < 4; u++) p0[u] = i0[k + u];
        #pragma unroll
        for (int u = 0; u < 4; u++) p1[u] = i1[k + u];
        if (has3) {
            #pragma unroll
            for (int u = 0; u < 4; u++) p2[u] = i2[k + u];
        }
        #pragma unroll
        for (int u = 0; u < 4; u++) {
            a0 = fmaf(p0[u], w[u], a0);
            a1 = fmaf(p1[u], w[u], a1);
            if (has3) a2 = fmaf(p2[u], w[u], a2);
        }
    }
    __syncthreads();                               // dinv ready
    ys[c0 * 8 + j] = dinv[c0] * a0;
    ys[c1 * 8 + j] = dinv[c1] * a1;
    if (has3) ys[c2 * 8 + j] = dinv[c2] * a2;
    __syncthreads();                               // ys visible

    // x1 = leaky(dinv[c] * sum_e A[e,c]*ys[e]); store xs = dinv*x1
    float b0 = 0.f, b1 = 0.f, b2 = 0.f;
    #pragma unroll 4
    for (int e = 0; e < 80; e++) {
        float y = ys[e * 8 + j];
        b0 = fmaf(A[e * 80 + c0], y, b0);
        b1 = fmaf(A[e * 80 + c1], y, b1);
        if (has3) b2 = fmaf(A[e * 80 + c2], y, b2);
    }
    b0 *= dinv[c0];
    b1 *= dinv[c1];
    b2 *= has3 ? dinv[c2] : 0.f;
    if (b0 < 0.f) b0 *= 0.2f;
    if (b1 < 0.f) b1 *= 0.2f;
    if (b2 < 0.f) b2 *= 0.2f;
    __syncthreads();                               // ys fully consumed
    xs[c0 * 8 + j] = dinv[c0] * b0;
    xs[c1 * 8 + j] = dinv[c1] * b1;
    if (has3) xs[c2 * 8 + j] = dinv[c2] * b2;
    __syncthreads();                               // xs visible

    // x2 = dinv[c] * sum_e A[e,c]*xs[e] -> bf16 global
    float d0 = 0.f, d1 = 0.f, d2 = 0.f;
    #pragma unroll 4
    for (int e = 0; e < 80; e++) {
        float x = xs[e * 8 + j];
        d0 = fmaf(A[e * 80 + c0], x, d0);
        d1 = fmaf(A[e * 80 + c1], x, d1);
        if (has3) d2 = fmaf(A[e * 80 + c2], x, d2);
    }
    x2b[c0 * 1024 + j0 + j] = f2bf(d0 * dinv[c0]);
    x2b[c1 * 1024 + j0 + j] = f2bf(d1 * dinv[c1]);
    if (has3) x2b[c2 * 1024 + j0 + j] = f2bf(d2 * dinv[c2]);
}

// =================== MFMA GEMMs (256 thr, BN=16, in-block 4-way K-split) ===================
// W in [N][K] row-major (K-contiguous): fast float4 loads.
template <int MF>
__device__ __forceinline__ void gemm_block(int bx, const unsigned short* __restrict__ X,
                                           const float* __restrict__ W,
                                           const float* __restrict__ bias,
                                           float* __restrict__ outf,
                                           unsigned short* __restrict__ outb,
                                           int N, int K, float (*red)[64][21]) {
    int tid = threadIdx.x;
    int ks = tid >> 6, lane = tid & 63;           // wave = k-split
    int n = bx * 16 + (lane & 15);
    int rowa = lane & 15;
    int koff = (lane >> 4) * 8;
    int Kc = K >> 2;
    int k0 = ks * Kc;

    f32x4 acc[MF];
    #pragma unroll
    for (int i = 0; i < MF; i++) acc[i] = (f32x4)(0.f);

    const float* wrow = W + (size_t)n * K;

    #pragma unroll 2
    for (int k = k0; k < k0 + Kc; k += 32) {
        float4 w0 = *(const float4*)(wrow + k + koff);
        float4 w1 = *(const float4*)(wrow + k + koff + 4);
        u16x8 bu;
        bu[0] = f2bf(w0.x); bu[1] = f2bf(w0.y); bu[2] = f2bf(w0.z); bu[3] = f2bf(w0.w);
        bu[4] = f2bf(w1.x); bu[5] = f2bf(w1.y); bu[6] = f2bf(w1.z); bu[7] = f2bf(w1.w);
        bf16x8 bf = __builtin_bit_cast(bf16x8, bu);
        #pragma unroll
        for (int mf = 0; mf < MF; mf++) {
            u16x8 au = *(const u16x8*)(X + (size_t)(mf * 16 + rowa) * K + k + koff);
            acc[mf] = __builtin_amdgcn_mfma_f32_16x16x32_bf16(
                __builtin_bit_cast(bf16x8, au), bf, acc[mf], 0, 0, 0);
        }
    }

    #pragma unroll
    for (int mf = 0; mf < MF; mf++)
        #pragma unroll
        for (int i = 0; i < 4; i++)
            red[ks][lane][mf * 4 + i] = acc[mf][i];
    __syncthreads();

    int lane2 = tid & 63, sg = tid >> 6;
    int n2 = bx * 16 + (lane2 & 15);
    float b = bias ? bias[n2] : 0.f;
    #pragma unroll
    for (int mf = 0; mf < MF; mf++) {
        int slot = mf * 4 + sg;
        float s = red[0][lane2][slot] + red[1][lane2][slot]
                + red[2][lane2][slot] + red[3][lane2][slot] + b;
        int row = mf * 16 + (lane2 >> 4) * 4 + sg;
        size_t o = (size_t)row * N + n2;
        if (outf) outf[o] = s;
        if (outb) outb[o] = f2bf(s);
    }
}

// W in [K][N] row-major (N-contiguous): strided B loads — no transpose needed.
template <int MF>
__device__ __forceinline__ void gemm_block_kn(int bx, const unsigned short* __restrict__ X,
                                              const float* __restrict__ Wkn,
                                              const float* __restrict__ bias,
                                              float* __restrict__ outf,
                                              unsigned short* __restrict__ outb,
                                              int N, int K, float (*red)[64][21]) {
    int tid = threadIdx.x;
    int ks = tid >> 6, lane = tid & 63;
    int n = bx * 16 + (lane & 15);
    int rowa = lane & 15;
    int koff = (lane >> 4) * 8;
    int Kc = K >> 2;
    int k0 = ks * Kc;

    f32x4 acc[MF];
    #pragma unroll
    for (int i = 0; i < MF; i++) acc[i] = (f32x4)(0.f);

    #pragma unroll 2
    for (int k = k0; k < k0 + Kc; k += 32) {
        float w[8];
        #pragma unroll
        for (int i = 0; i < 8; i++) w[i] = Wkn[(size_t)(k + koff + i) * N + n];
        u16x8 bu;
        #pragma unroll
        for (int i = 0; i < 8; i++) bu[i] = f2bf(w[i]);
        bf16x8 bf = __builtin_bit_cast(bf16x8, bu);
        #pragma unroll
        for (int mf = 0; mf < MF; mf++) {
            u16x8 au = *(const u16x8*)(X + (size_t)(mf * 16 + rowa) * K + k + koff);
            acc[mf] = __builtin_amdgcn_mfma_f32_16x16x32_bf16(
                __builtin_bit_cast(bf16x8, au), bf, acc[mf], 0, 0, 0);
        }
    }

    #pragma unroll
    for (int mf = 0; mf < MF; mf++)
        #pragma unroll
        for (int i = 0; i < 4; i++)
            red[ks][lane][mf * 4 + i] = acc[mf][i];
    __syncthreads();

    int lane2 = tid & 63, sg = tid >> 6;
    int n2 = bx * 16 + (lane2 & 15);
    float b = bias ? bias[n2] : 0.f;
    #pragma unroll
    for (int mf = 0; mf < MF; mf++) {
        int slot = mf * 4 + sg;
        float s = red[0][lane2][slot] + red[1][lane2][slot]
                + red[2][lane2][slot] + red[3][lane2][slot] + b;
        int row = mf * 16 + (lane2 >> 4) * 4 + sg;
        size_t o = (size_t)row * N + n2;
        if (outf) outf[o] = s;
        if (outb) outb[o] = f2bf(s);
    }
}

// =================== kernels (5 dispatches) ===================

// D1: gcn-front (0-127) | maxpool (128-4223). LDS only 5.4 KB now.
__global__ __launch_bounds__(256, 4) void kD1(const float* __restrict__ feature,
                                              unsigned short* __restrict__ featb,
                                              const float* __restrict__ inp,
                                              const float* __restrict__ W1,
                                              const float* __restrict__ A,
                                              unsigned short* __restrict__ x2b) {
    __shared__ __align__(16) float smem[1360];    // 5.4 KB
    int b = blockIdx.x;
    if (b < 128) gcn_front_role(b, inp, W1, A, x2b, smem);
    else         maxpool_role(b - 128, feature, featb);
}

// D2: img units (0-511, [N][K] fast path) | xb units (512-639, [K][N] strided)
__global__ __launch_bounds__(256, 4) void kD2(const unsigned short* __restrict__ featb,
                                              const float* __restrict__ W_img,
                                              const float* __restrict__ b_img,
                                              float* __restrict__ img,
                                              const unsigned short* __restrict__ x2b,
                                              const float* __restrict__ W_gc2,
                                              unsigned short* __restrict__ xb) {
    __shared__ __align__(16) float red[4][64][21];   // 21.5 KB
    int b = blockIdx.x;
    if (b < 512) gemm_block<4>(b, featb, W_img, b_img, img, nullptr, 8192, 2048, red);
    else         gemm_block_kn<5>(b - 512, x2b, W_gc2, nullptr, nullptr, xb, 2048, 1024, red);
}

// D3: cls = xb @ W_cls^T + b_cls (512 blocks)
__global__ __launch_bounds__(256, 4) void kD3(const unsigned short* __restrict__ xb,
                                              const float* __restrict__ W_cls,
                                              const float* __restrict__ b_cls,
                                              float* __restrict__ cls) {
    __shared__ __align__(16) float red[4][64][21];
    gemm_block<5>(blockIdx.x, xb, W_cls, b_cls, cls, nullptr, 8192, 2048, red);
}

// D4: G[c2,j] = sum_c cls[c,j] * W_ml[c2, c*1024 + (j>>3)]; 640 blocks (64 o x 10 c2)
__global__ __launch_bounds__(256, 4) void kD4(const float* __restrict__ cls,
                                              const float* __restrict__ W_ml,
                                              float* __restrict__ G) {
    __shared__ __align__(16) float smem[8 * 80 * 16];   // 40 KB
    float (*wml)[80][16] = (float (*)[80][16])smem;
    int idx = blockIdx.x;
    int o0  = (idx & 63) * 16;
    int c2b = (idx >> 6) * 8;
    int j0  = o0 * 8;
    for (int i = threadIdx.x; i < 8 * 80 * 16; i += 256) {
        int ol = i & 15, c = (i >> 4) % 80, c2 = i / 1280;
        wml[c2][c][ol] = W_ml[(size_t)(c2b + c2) * 81920 + c * 1024 + o0 + ol];
    }
    __syncthreads();
    int jl  = threadIdx.x & 127;
    int c2h = (threadIdx.x >> 7) * 4;
    int ol  = jl >> 3;
    float acc[4] = {0.f, 0.f, 0.f, 0.f};
    for (int c = 0; c < 80; c++) {
        float cv = cls[(size_t)c * 8192 + j0 + jl];
        #pragma unroll
        for (int i = 0; i < 4; i++) acc[i] = fmaf(cv, wml[c2h + i][c][ol], acc[i]);
    }
    #pragma unroll
    for (int i = 0; i < 4; i++) G[(size_t)(c2b + c2h + i) * 8192 + j0 + jl] = acc[i];
}

// D5: out[b,c2] = sum_j img[b,j]*G[c2,j] + b_ml[c2]
// 640 blocks = b(64) x cg(10); 4 waves = k-quarters; acc[8] scalars/thread.
__global__ __launch_bounds__(256, 2) void kD5(const float* __restrict__ img,
                                              const float* __restrict__ G,
                                              const float* __restrict__ b_ml,
                                              float* __restrict__ out) {
    __shared__ float sm[4][8];
    int b = blockIdx.x / 10, cg = blockIdx.x % 10;
    int kc = threadIdx.x >> 6, lane = threadIdx.x & 63;
    const float* ib = img + (size_t)b * 8192 + kc * 2048;
    const float* gb = G + (size_t)(cg * 8) * 8192 + kc * 2048;
    float acc[8] = {0.f, 0.f, 0.f, 0.f, 0.f, 0.f, 0.f, 0.f};
    #pragma unroll
    for (int step = 0; step < 8; step++) {
        int k = step * 256 + lane * 4;
        float4 iv = *(const float4*)(ib + k);
        float4 gv[8];
        #pragma unroll
        for (int i = 0; i < 8; i++) gv[i] = *(const float4*)(gb + (size_t)i * 8192 + k);
        #pragma unroll
        for (int i = 0; i < 8; i++) {
            acc[i] = fmaf(iv.x, gv[i].x, acc[i]);
            acc[i] = fmaf(iv.y, gv[i].y, acc[i]);
            acc[i] = fmaf(iv.z, gv[i].z, acc[i]);
            acc[i] = fmaf(iv.w, gv[i].w, acc[i]);
        }
    }
    #pragma unroll
    for (int i = 0; i < 8; i++) {
        float v = acc[i];
        #pragma unroll
        for (int off = 32; off; off >>= 1) v += __shfl_xor(v, off);
        if (lane == 0) sm[kc][i] = v;
    }
    __syncthreads();
    if (threadIdx.x < 8) {
        int i = threadIdx.x;
        float s = b_ml[cg * 8 + i] + sm[0][i] + sm[1][i] + sm[2][i] + sm[3][i];
        out[(size_t)b * 80 + cg * 8 + i] = s;
    }
}

// ---------------- launch ----------------
extern "C" void kernel_launch(void* const* d_in, const int* in_sizes, int n_in,
                              void* d_out, int out_size, void* d_ws, size_t ws_size,
                              hipStream_t stream) {
    (void)in_sizes; (void)n_in; (void)out_size; (void)ws_size;
    const float* feature = (const float*)d_in[0];
    const float* inp     = (const float*)d_in[1];
    const float* A       = (const float*)d_in[2];
    const float* W_gc1   = (const float*)d_in[3];
    const float* W_gc2   = (const float*)d_in[4];
    const float* W_img   = (const float*)d_in[5];
    const float* b_img   = (const float*)d_in[6];
    const float* W_cls   = (const float*)d_in[7];
    const float* b_cls   = (const float*)d_in[8];
    const float* W_ml    = (const float*)d_in[9];
    const float* b_ml    = (const float*)d_in[10];
    float* out = (float*)d_out;
    char*  ws  = (char*)d_ws;

    unsigned short* featb = (unsigned short*)(ws + OFF_FEATB);
    unsigned short* x2b   = (unsigned short*)(ws + OFF_X2B);
    unsigned short* xb    = (unsigned short*)(ws + OFF_XB);
    float* img  = (float*)(ws + OFF_IMG);
    float* cls  = (float*)(ws + OFF_CLS);
    float* G    = (float*)(ws + OFF_G);

    kD1<<<4224, 256, 0, stream>>>(feature, featb, inp, W_gc1, A, x2b);
    kD2<<<640,  256, 0, stream>>>(featb, W_img, b_img, img, x2b, W_gc2, xb);
    kD3<<<512,  256, 0, stream>>>(xb, W_cls, b_cls, cls);
    kD4<<<640,  256, 0, stream>>>(cls, W_ml, G);
    kD5<<<640,  256, 0, stream>>>(img, G, b_ml, out);
}

// Round 13
// 156.490 us; speedup vs baseline: 1.0069x; 1.0069x over previous
//
#include <hip/hip_runtime.h>
#include <hip/hip_bf16.h>
#include <cstdint>
#include <cstddef>

// ---------------- types / helpers ----------------
typedef float  f32x4  __attribute__((ext_vector_type(4)));
typedef __bf16 bf16x8 __attribute__((ext_vector_type(8)));
typedef unsigned short u16x8 __attribute__((ext_vector_type(8)));

__device__ __forceinline__ unsigned short f2bf(float f) {
    unsigned u = __float_as_uint(f);
    u += 0x7FFFu + ((u >> 16) & 1u);   // round-to-nearest-even
    return (unsigned short)(u >> 16);
}

// ---------------- problem constants ----------------
// B=64, C=80, IN_CH=300, J=8192, S=8, OUT=1024
// feature [64,2048,14,14] (131072 rows of 196 floats), out [64,80]

// ---------------- ws layout (bytes) ----------------
constexpr size_t OFF_FEATB = 0;          // 64*2048 bf16  = 262144
constexpr size_t OFF_X2B   = 262144;     // 80*1024 bf16  = 163840
constexpr size_t OFF_XB    = 425984;     // 80*2048 bf16  = 327680
constexpr size_t OFF_IMG   = 753664;     // 64*8192 f32   = 2097152
constexpr size_t OFF_CLS   = 2850816;    // 80*8192 f32   = 2621440
constexpr size_t OFF_G     = 5472256;    // 80*8192 f32   = 2621440

// =================== D1 roles (256 threads) ===================

// maxpool r13: LDS-staged, PERFECTLY LINEAR global reads.
// Block owns 32 rows = 1568 float4 = 25088 B (128-aligned since 25088 = 196*128).
// Phase 1: flat copy, lane i <-> float4 i — every wave-load is 64 consecutive
// float4s (1 KB, aligned): the same access shape that streams 3.7-4.5 TB/s in
// kD2/kD3. (Rounds 2-12: per-row scattered loads pinned at ~1.3 TB/s
// regardless of ILP/occupancy — pattern, not latency, was the wall.)
// Phase 2: reduce rows out of LDS (8 thr/row), shfl combine. Max is
// associative -> bit-identical result.
__device__ __forceinline__ void maxpool_role(int vbid, const float* __restrict__ feature,
                                             unsigned short* __restrict__ featb,
                                             float4* tile /* 1568 float4 = 25.1 KB */) {
    int t = threadIdx.x;
    const float4* src = (const float4*)(feature + (size_t)vbid * 32 * 196);
    #pragma unroll
    for (int pass = 0; pass < 6; ++pass)
        tile[pass * 256 + t] = src[pass * 256 + t];
    if (t < 32) tile[1536 + t] = src[1536 + t];
    __syncthreads();

    int r = t >> 3, q = t & 7;                    // 32 rows x 8 threads
    const float4* row = tile + r * 49;
    float4 v0 = row[q],      v1 = row[q + 8],  v2 = row[q + 16];
    float4 v3 = row[q + 24], v4 = row[q + 32], v5 = row[q + 40];
    float m0 = fmaxf(fmaxf(v0.x, v0.y), fmaxf(v0.z, v0.w));
    float m1 = fmaxf(fmaxf(v1.x, v1.y), fmaxf(v1.z, v1.w));
    float m2 = fmaxf(fmaxf(v2.x, v2.y), fmaxf(v2.z, v2.w));
    float m3 = fmaxf(fmaxf(v3.x, v3.y), fmaxf(v3.z, v3.w));
    float m4 = fmaxf(fmaxf(v4.x, v4.y), fmaxf(v4.z, v4.w));
    float m5 = fmaxf(fmaxf(v5.x, v5.y), fmaxf(v5.z, v5.w));
    float m = fmaxf(fmaxf(fmaxf(m0, m1), fmaxf(m2, m3)), fmaxf(m4, m5));
    if (q == 0) {                                  // col 48 tail (floats 192..195)
        float4 d = row[48];
        m = fmaxf(m, fmaxf(fmaxf(d.x, d.y), fmaxf(d.z, d.w)));
    }
    #pragma unroll
    for (int off = 1; off < 8; off <<= 1) m = fmaxf(m, __shfl_xor(m, off));
    if (q == 0) featb[vbid * 32 + r] = f2bf(m);
}

// GCN front (unchanged from r11): LDS-lean, A read via L1, factored dinv.
// Block owns 8 j-columns (j0 = idx*8); thread (j = t&7, slot = t>>3) owns
// c = {slot, slot+32, slot+64(<80)}.
__device__ __forceinline__ void gcn_front_role(int idx, const float* __restrict__ inp,
                                               const float* __restrict__ W1,
                                               const float* __restrict__ A,
                                               unsigned short* __restrict__ x2b,
                                               float* smem) {
    float* dinv = smem;            // [80]
    float* ys   = smem + 80;       // [80][8]  dinv[e]*y0[e][j]
    float* xs   = smem + 720;      // [80][8]  dinv[e]*x1[e][j]
    int t = threadIdx.x;
    int j = t & 7, slot = t >> 3;                 // slot 0..31
    int j0 = idx * 8;
    int c0 = slot, c1 = slot + 32, c2 = slot + 64;
    bool has3 = (slot < 16);                      // wave-uniform

    if (t < 80) {
        const float4* ar = (const float4*)(A + t * 80);
        float4 s4 = {0.f, 0.f, 0.f, 0.f};
        #pragma unroll
        for (int q = 0; q < 20; q++) {
            float4 v = ar[q];
            s4.x += v.x; s4.y += v.y; s4.z += v.z; s4.w += v.w;
        }
        dinv[t] = 1.0f / sqrtf(s4.x + s4.y + s4.z + s4.w);
    }

    // y0: 300 serial k, W1 column loads batched 4-deep
    const float* wcol = W1 + j0 + j;
    const float* i0 = inp + c0 * 300;
    const float* i1 = inp + c1 * 300;
    const float* i2 = inp + c2 * 300;
    float a0 = 0.f, a1 = 0.f, a2 = 0.f;
    for (int k = 0; k < 300; k += 4) {
        float w[4], p0[4], p1[4], p2[4];
        #pragma unroll
        for (int u = 0; u < 4; u++) w[u] = wcol[(size_t)(k + u) * 1024];
        #pragma unroll
        for (int u = 0; u < 4; u++) p0[u] = i0[k + u];
        #pragma unroll
        for (int u = 0; u < 4; u++) p1[u] = i1[k + u];
        if (has3) {
            #pragma unroll
            for (int u = 0; u < 4; u++) p2[u] = i2[k + u];
        }
        #pragma unroll
        for (int u = 0; u < 4; u++) {
            a0 = fmaf(p0[u], w[u], a0);
            a1 = fmaf(p1[u], w[u], a1);
            if (has3) a2 = fmaf(p2[u], w[u], a2);
        }
    }
    __syncthreads();                               // dinv ready
    ys[c0 * 8 + j] = dinv[c0] * a0;
    ys[c1 * 8 + j] = dinv[c1] * a1;
    if (has3) ys[c2 * 8 + j] = dinv[c2] * a2;
    __syncthreads();                               // ys visible

    // x1 = leaky(dinv[c] * sum_e A[e,c]*ys[e]); store xs = dinv*x1
    float b0 = 0.f, b1 = 0.f, b2 = 0.f;
    #pragma unroll 4
    for (int e = 0; e < 80; e++) {
        float y = ys[e * 8 + j];
        b0 = fmaf(A[e * 80 + c0], y, b0);
        b1 = fmaf(A[e * 80 + c1], y, b1);
        if (has3) b2 = fmaf(A[e * 80 + c2], y, b2);
    }
    b0 *= dinv[c0];
    b1 *= dinv[c1];
    b2 *= has3 ? dinv[c2] : 0.f;
    if (b0 < 0.f) b0 *= 0.2f;
    if (b1 < 0.f) b1 *= 0.2f;
    if (b2 < 0.f) b2 *= 0.2f;
    __syncthreads();                               // ys fully consumed
    xs[c0 * 8 + j] = dinv[c0] * b0;
    xs[c1 * 8 + j] = dinv[c1] * b1;
    if (has3) xs[c2 * 8 + j] = dinv[c2] * b2;
    __syncthreads();                               // xs visible

    // x2 = dinv[c] * sum_e A[e,c]*xs[e] -> bf16 global
    float d0 = 0.f, d1 = 0.f, d2 = 0.f;
    #pragma unroll 4
    for (int e = 0; e < 80; e++) {
        float x = xs[e * 8 + j];
        d0 = fmaf(A[e * 80 + c0], x, d0);
        d1 = fmaf(A[e * 80 + c1], x, d1);
        if (has3) d2 = fmaf(A[e * 80 + c2], x, d2);
    }
    x2b[c0 * 1024 + j0 + j] = f2bf(d0 * dinv[c0]);
    x2b[c1 * 1024 + j0 + j] = f2bf(d1 * dinv[c1]);
    if (has3) x2b[c2 * 1024 + j0 + j] = f2bf(d2 * dinv[c2]);
}

// =================== MFMA GEMMs (256 thr, BN=16, in-block 4-way K-split) ===================
// W in [N][K] row-major (K-contiguous): fast float4 loads.
template <int MF>
__device__ __forceinline__ void gemm_block(int bx, const unsigned short* __restrict__ X,
                                           const float* __restrict__ W,
                                           const float* __restrict__ bias,
                                           float* __restrict__ outf,
                                           unsigned short* __restrict__ outb,
                                           int N, int K, float (*red)[64][21]) {
    int tid = threadIdx.x;
    int ks = tid >> 6, lane = tid & 63;           // wave = k-split
    int n = bx * 16 + (lane & 15);
    int rowa = lane & 15;
    int koff = (lane >> 4) * 8;
    int Kc = K >> 2;
    int k0 = ks * Kc;

    f32x4 acc[MF];
    #pragma unroll
    for (int i = 0; i < MF; i++) acc[i] = (f32x4)(0.f);

    const float* wrow = W + (size_t)n * K;

    #pragma unroll 2
    for (int k = k0; k < k0 + Kc; k += 32) {
        float4 w0 = *(const float4*)(wrow + k + koff);
        float4 w1 = *(const float4*)(wrow + k + koff + 4);
        u16x8 bu;
        bu[0] = f2bf(w0.x); bu[1] = f2bf(w0.y); bu[2] = f2bf(w0.z); bu[3] = f2bf(w0.w);
        bu[4] = f2bf(w1.x); bu[5] = f2bf(w1.y); bu[6] = f2bf(w1.z); bu[7] = f2bf(w1.w);
        bf16x8 bf = __builtin_bit_cast(bf16x8, bu);
        #pragma unroll
        for (int mf = 0; mf < MF; mf++) {
            u16x8 au = *(const u16x8*)(X + (size_t)(mf * 16 + rowa) * K + k + koff);
            acc[mf] = __builtin_amdgcn_mfma_f32_16x16x32_bf16(
                __builtin_bit_cast(bf16x8, au), bf, acc[mf], 0, 0, 0);
        }
    }

    #pragma unroll
    for (int mf = 0; mf < MF; mf++)
        #pragma unroll
        for (int i = 0; i < 4; i++)
            red[ks][lane][mf * 4 + i] = acc[mf][i];
    __syncthreads();

    int lane2 = tid & 63, sg = tid >> 6;
    int n2 = bx * 16 + (lane2 & 15);
    float b = bias ? bias[n2] : 0.f;
    #pragma unroll
    for (int mf = 0; mf < MF; mf++) {
        int slot = mf * 4 + sg;
        float s = red[0][lane2][slot] + red[1][lane2][slot]
                + red[2][lane2][slot] + red[3][lane2][slot] + b;
        int row = mf * 16 + (lane2 >> 4) * 4 + sg;
        size_t o = (size_t)row * N + n2;
        if (outf) outf[o] = s;
        if (outb) outb[o] = f2bf(s);
    }
}

// W in [K][N] row-major (N-contiguous): strided B loads — no transpose needed.
template <int MF>
__device__ __forceinline__ void gemm_block_kn(int bx, const unsigned short* __restrict__ X,
                                              const float* __restrict__ Wkn,
                                              const float* __restrict__ bias,
                                              float* __restrict__ outf,
                                              unsigned short* __restrict__ outb,
                                              int N, int K, float (*red)[64][21]) {
    int tid = threadIdx.x;
    int ks = tid >> 6, lane = tid & 63;
    int n = bx * 16 + (lane & 15);
    int rowa = lane & 15;
    int koff = (lane >> 4) * 8;
    int Kc = K >> 2;
    int k0 = ks * Kc;

    f32x4 acc[MF];
    #pragma unroll
    for (int i = 0; i < MF; i++) acc[i] = (f32x4)(0.f);

    #pragma unroll 2
    for (int k = k0; k < k0 + Kc; k += 32) {
        float w[8];
        #pragma unroll
        for (int i = 0; i < 8; i++) w[i] = Wkn[(size_t)(k + koff + i) * N + n];
        u16x8 bu;
        #pragma unroll
        for (int i = 0; i < 8; i++) bu[i] = f2bf(w[i]);
        bf16x8 bf = __builtin_bit_cast(bf16x8, bu);
        #pragma unroll
        for (int mf = 0; mf < MF; mf++) {
            u16x8 au = *(const u16x8*)(X + (size_t)(mf * 16 + rowa) * K + k + koff);
            acc[mf] = __builtin_amdgcn_mfma_f32_16x16x32_bf16(
                __builtin_bit_cast(bf16x8, au), bf, acc[mf], 0, 0, 0);
        }
    }

    #pragma unroll
    for (int mf = 0; mf < MF; mf++)
        #pragma unroll
        for (int i = 0; i < 4; i++)
            red[ks][lane][mf * 4 + i] = acc[mf][i];
    __syncthreads();

    int lane2 = tid & 63, sg = tid >> 6;
    int n2 = bx * 16 + (lane2 & 15);
    float b = bias ? bias[n2] : 0.f;
    #pragma unroll
    for (int mf = 0; mf < MF; mf++) {
        int slot = mf * 4 + sg;
        float s = red[0][lane2][slot] + red[1][lane2][slot]
                + red[2][lane2][slot] + red[3][lane2][slot] + b;
        int row = mf * 16 + (lane2 >> 4) * 4 + sg;
        size_t o = (size_t)row * N + n2;
        if (outf) outf[o] = s;
        if (outb) outb[o] = f2bf(s);
    }
}

// =================== kernels (5 dispatches) ===================

// D1: gcn-front (0-127) | maxpool (128-4223). LDS 25.1 KB union.
__global__ __launch_bounds__(256, 4) void kD1(const float* __restrict__ feature,
                                              unsigned short* __restrict__ featb,
                                              const float* __restrict__ inp,
                                              const float* __restrict__ W1,
                                              const float* __restrict__ A,
                                              unsigned short* __restrict__ x2b) {
    __shared__ __align__(16) float smem[6272];    // 25.1 KB (1568 float4)
    int b = blockIdx.x;
    if (b < 128) gcn_front_role(b, inp, W1, A, x2b, smem);
    else         maxpool_role(b - 128, feature, featb, (float4*)smem);
}

// D2: img units (0-511, [N][K] fast path) | xb units (512-639, [K][N] strided)
__global__ __launch_bounds__(256, 4) void kD2(const unsigned short* __restrict__ featb,
                                              const float* __restrict__ W_img,
                                              const float* __restrict__ b_img,
                                              float* __restrict__ img,
                                              const unsigned short* __restrict__ x2b,
                                              const float* __restrict__ W_gc2,
                                              unsigned short* __restrict__ xb) {
    __shared__ __align__(16) float red[4][64][21];   // 21.5 KB
    int b = blockIdx.x;
    if (b < 512) gemm_block<4>(b, featb, W_img, b_img, img, nullptr, 8192, 2048, red);
    else         gemm_block_kn<5>(b - 512, x2b, W_gc2, nullptr, nullptr, xb, 2048, 1024, red);
}

// D3: cls = xb @ W_cls^T + b_cls (512 blocks)
__global__ __launch_bounds__(256, 4) void kD3(const unsigned short* __restrict__ xb,
                                              const float* __restrict__ W_cls,
                                              const float* __restrict__ b_cls,
                                              float* __restrict__ cls) {
    __shared__ __align__(16) float red[4][64][21];
    gemm_block<5>(blockIdx.x, xb, W_cls, b_cls, cls, nullptr, 8192, 2048, red);
}

// D4: G[c2,j] = sum_c cls[c,j] * W_ml[c2, c*1024 + (j>>3)]; 640 blocks (64 o x 10 c2)
__global__ __launch_bounds__(256, 4) void kD4(const float* __restrict__ cls,
                                              const float* __restrict__ W_ml,
                                              float* __restrict__ G) {
    __shared__ __align__(16) float smem[8 * 80 * 16];   // 40 KB
    float (*wml)[80][16] = (float (*)[80][16])smem;
    int idx = blockIdx.x;
    int o0  = (idx & 63) * 16;
    int c2b = (idx >> 6) * 8;
    int j0  = o0 * 8;
    for (int i = threadIdx.x; i < 8 * 80 * 16; i += 256) {
        int ol = i & 15, c = (i >> 4) % 80, c2 = i / 1280;
        wml[c2][c][ol] = W_ml[(size_t)(c2b + c2) * 81920 + c * 1024 + o0 + ol];
    }
    __syncthreads();
    int jl  = threadIdx.x & 127;
    int c2h = (threadIdx.x >> 7) * 4;
    int ol  = jl >> 3;
    float acc[4] = {0.f, 0.f, 0.f, 0.f};
    for (int c = 0; c < 80; c++) {
        float cv = cls[(size_t)c * 8192 + j0 + jl];
        #pragma unroll
        for (int i = 0; i < 4; i++) acc[i] = fmaf(cv, wml[c2h + i][c][ol], acc[i]);
    }
    #pragma unroll
    for (int i = 0; i < 4; i++) G[(size_t)(c2b + c2h + i) * 8192 + j0 + jl] = acc[i];
}

// D5: out[b,c2] = sum_j img[b,j]*G[c2,j] + b_ml[c2]
// 640 blocks = b(64) x cg(10); 4 waves = k-quarters; acc[8] scalars/thread.
__global__ __launch_bounds__(256, 2) void kD5(const float* __restrict__ img,
                                              const float* __restrict__ G,
                                              const float* __restrict__ b_ml,
                                              float* __restrict__ out) {
    __shared__ float sm[4][8];
    int b = blockIdx.x / 10, cg = blockIdx.x % 10;
    int kc = threadIdx.x >> 6, lane = threadIdx.x & 63;
    const float* ib = img + (size_t)b * 8192 + kc * 2048;
    const float* gb = G + (size_t)(cg * 8) * 8192 + kc * 2048;
    float acc[8] = {0.f, 0.f, 0.f, 0.f, 0.f, 0.f, 0.f, 0.f};
    #pragma unroll
    for (int step = 0; step < 8; step++) {
        int k = step * 256 + lane * 4;
        float4 iv = *(const float4*)(ib + k);
        float4 gv[8];
        #pragma unroll
        for (int i = 0; i < 8; i++) gv[i] = *(const float4*)(gb + (size_t)i * 8192 + k);
        #pragma unroll
        for (int i = 0; i < 8; i++) {
            acc[i] = fmaf(iv.x, gv[i].x, acc[i]);
            acc[i] = fmaf(iv.y, gv[i].y, acc[i]);
            acc[i] = fmaf(iv.z, gv[i].z, acc[i]);
            acc[i] = fmaf(iv.w, gv[i].w, acc[i]);
        }
    }
    #pragma unroll
    for (int i = 0; i < 8; i++) {
        float v = acc[i];
        #pragma unroll
        for (int off = 32; off; off >>= 1) v += __shfl_xor(v, off);
        if (lane == 0) sm[kc][i] = v;
    }
    __syncthreads();
    if (threadIdx.x < 8) {
        int i = threadIdx.x;
        float s = b_ml[cg * 8 + i] + sm[0][i] + sm[1][i] + sm[2][i] + sm[3][i];
        out[(size_t)b * 80 + cg * 8 + i] = s;
    }
}

// ---------------- launch ----------------
extern "C" void kernel_launch(void* const* d_in, const int* in_sizes, int n_in,
                              void* d_out, int out_size, void* d_ws, size_t ws_size,
                              hipStream_t stream) {
    (void)in_sizes; (void)n_in; (void)out_size; (void)ws_size;
    const float* feature = (const float*)d_in[0];
    const float* inp     = (const float*)d_in[1];
    const float* A       = (const float*)d_in[2];
    const float* W_gc1   = (const float*)d_in[3];
    const float* W_gc2   = (const float*)d_in[4];
    const float* W_img   = (const float*)d_in[5];
    const float* b_img   = (const float*)d_in[6];
    const float* W_cls   = (const float*)d_in[7];
    const float* b_cls   = (const float*)d_in[8];
    const float* W_ml    = (const float*)d_in[9];
    const float* b_ml    = (const float*)d_in[10];
    float* out = (float*)d_out;
    char*  ws  = (char*)d_ws;

    unsigned short* featb = (unsigned short*)(ws + OFF_FEATB);
    unsigned short* x2b   = (unsigned short*)(ws + OFF_X2B);
    unsigned short* xb    = (unsigned short*)(ws + OFF_XB);
    float* img  = (float*)(ws + OFF_IMG);
    float* cls  = (float*)(ws + OFF_CLS);
    float* G    = (float*)(ws + OFF_G);

    kD1<<<4224, 256, 0, stream>>>(feature, featb, inp, W_gc1, A, x2b);
    kD2<<<640,  256, 0, stream>>>(featb, W_img, b_img, img, x2b, W_gc2, xb);
    kD3<<<512,  256, 0, stream>>>(xb, W_cls, b_cls, cls);
    kD4<<<640,  256, 0, stream>>>(cls, W_ml, G);
    kD5<<<640,  256, 0, stream>>>(img, G, b_ml, out);
}

// Round 14
// 132.324 us; speedup vs baseline: 1.1908x; 1.1826x over previous
//
#include <hip/hip_runtime.h>
#include <hip/hip_bf16.h>
#include <cstdint>
#include <cstddef>

// ---------------- types / helpers ----------------
typedef float  f32x4  __attribute__((ext_vector_type(4)));
typedef __bf16 bf16x8 __attribute__((ext_vector_type(8)));
typedef unsigned short u16x8 __attribute__((ext_vector_type(8)));

__device__ __forceinline__ unsigned short f2bf(float f) {
    unsigned u = __float_as_uint(f);
    u += 0x7FFFu + ((u >> 16) & 1u);   // round-to-nearest-even
    return (unsigned short)(u >> 16);
}

// ---------------- problem constants ----------------
// B=64, C=80, IN_CH=300, J=8192, S=8, OUT=1024
// feature [64,2048,14,14] (131072 rows of 196 floats), out [64,80]

// ---------------- ws layout (bytes) ----------------
constexpr size_t OFF_FEATB = 0;          // 64*2048 bf16  = 262144
constexpr size_t OFF_X2B   = 262144;     // 80*1024 bf16  = 163840
constexpr size_t OFF_XB    = 425984;     // 80*2048 bf16  = 327680
constexpr size_t OFF_IMG   = 753664;     // 64*8192 f32   = 2097152
constexpr size_t OFF_CLS   = 2850816;    // 80*8192 f32   = 2621440
constexpr size_t OFF_G     = 5472256;    // 80*8192 f32   = 2621440
constexpr size_t OFF_Y0    = 8093696;    // 80*1024 f32   = 327680

// =================== roles (256 threads) ===================

// maxpool (R13 LDS-linear, kept): block copies 32 rows = 25088 B flat
// (lane i <-> float4 i, 1 KB aligned per wave-load), then reduces from LDS.
__device__ __forceinline__ void maxpool_role(int vbid, const float* __restrict__ feature,
                                             unsigned short* __restrict__ featb,
                                             float4* tile /* 1568 float4 */) {
    int t = threadIdx.x;
    const float4* src = (const float4*)(feature + (size_t)vbid * 32 * 196);
    #pragma unroll
    for (int pass = 0; pass < 6; ++pass)
        tile[pass * 256 + t] = src[pass * 256 + t];
    if (t < 32) tile[1536 + t] = src[1536 + t];
    __syncthreads();

    int r = t >> 3, q = t & 7;                    // 32 rows x 8 threads
    const float4* row = tile + r * 49;
    float4 v0 = row[q],      v1 = row[q + 8],  v2 = row[q + 16];
    float4 v3 = row[q + 24], v4 = row[q + 32], v5 = row[q + 40];
    float m0 = fmaxf(fmaxf(v0.x, v0.y), fmaxf(v0.z, v0.w));
    float m1 = fmaxf(fmaxf(v1.x, v1.y), fmaxf(v1.z, v1.w));
    float m2 = fmaxf(fmaxf(v2.x, v2.y), fmaxf(v2.z, v2.w));
    float m3 = fmaxf(fmaxf(v3.x, v3.y), fmaxf(v3.z, v3.w));
    float m4 = fmaxf(fmaxf(v4.x, v4.y), fmaxf(v4.z, v4.w));
    float m5 = fmaxf(fmaxf(v5.x, v5.y), fmaxf(v5.z, v5.w));
    float m = fmaxf(fmaxf(fmaxf(m0, m1), fmaxf(m2, m3)), fmaxf(m4, m5));
    if (q == 0) {
        float4 d = row[48];
        m = fmaxf(m, fmaxf(fmaxf(d.x, d.y), fmaxf(d.z, d.w)));
    }
    #pragma unroll
    for (int off = 1; off < 8; off <<= 1) m = fmaxf(m, __shfl_xor(m, off));
    if (q == 0) featb[vbid * 32 + r] = f2bf(m);
}

// y0 role (R14: K-PARALLEL — the fix for the 85 us serial-K gcn gate).
// idx in [0,320): c = idx>>2, j-quarter = idx&3 (256 cols). 256 thr =
// 4 k-slices (75 each) x 64 j-float4. W1 loads: 64 lanes x 16 B = 1 KB
// contiguous per wave. 25 batches of 3 k -> ~3 us, not 85.
__device__ __forceinline__ void y0_role(int idx, const float* __restrict__ inp,
                                        const float* __restrict__ W1,
                                        float* __restrict__ y0g, float4* red) {
    int c = idx >> 2;
    int j = (idx & 3) * 256 + (threadIdx.x & 63) * 4;
    int ks = threadIdx.x >> 6;                    // 0..3
    const float* ir = inp + c * 300 + ks * 75;
    const float* wp = W1 + (size_t)(ks * 75) * 1024 + j;
    float4 acc = {0.f, 0.f, 0.f, 0.f};
    for (int k = 0; k < 75; k += 3) {
        float a0 = ir[k], a1 = ir[k + 1], a2 = ir[k + 2];
        float4 w0 = *(const float4*)(wp + (size_t)k * 1024);
        float4 w1 = *(const float4*)(wp + (size_t)(k + 1) * 1024);
        float4 w2 = *(const float4*)(wp + (size_t)(k + 2) * 1024);
        acc.x = fmaf(a0, w0.x, acc.x); acc.y = fmaf(a0, w0.y, acc.y);
        acc.z = fmaf(a0, w0.z, acc.z); acc.w = fmaf(a0, w0.w, acc.w);
        acc.x = fmaf(a1, w1.x, acc.x); acc.y = fmaf(a1, w1.y, acc.y);
        acc.z = fmaf(a1, w1.z, acc.z); acc.w = fmaf(a1, w1.w, acc.w);
        acc.x = fmaf(a2, w2.x, acc.x); acc.y = fmaf(a2, w2.y, acc.y);
        acc.z = fmaf(a2, w2.z, acc.z); acc.w = fmaf(a2, w2.w, acc.w);
    }
    int jq = threadIdx.x & 63;
    red[ks * 64 + jq] = __builtin_bit_cast(float4, acc);
    __syncthreads();
    if (ks == 0) {
        float4 s0 = red[jq], s1 = red[64 + jq], s2 = red[128 + jq], s3 = red[192 + jq];
        float4 s;
        s.x = s0.x + s1.x + s2.x + s3.x;
        s.y = s0.y + s1.y + s2.y + s3.y;
        s.z = s0.z + s1.z + s2.z + s3.z;
        s.w = s0.w + s1.w + s2.w + s3.w;
        *(float4*)(y0g + (size_t)c * 1024 + j) = s;
    }
}

// x1x2 role: K=80 chains only (A L1-resident, y0 from L2). Block owns 8
// j-cols; thread (j = t&7, slot = t>>3) owns c = {slot, slot+32, slot+64}.
__device__ __forceinline__ void x1x2_role(int idx, const float* __restrict__ y0g,
                                          const float* __restrict__ A,
                                          unsigned short* __restrict__ x2b,
                                          float* smem) {
    float* dinv = smem;            // [80]
    float* ys   = smem + 80;       // [80][8]
    float* xs   = smem + 720;      // [80][8]
    int t = threadIdx.x;
    int j = t & 7, slot = t >> 3;
    int j0 = idx * 8;
    int c0 = slot, c1 = slot + 32, c2 = slot + 64;
    bool has3 = (slot < 16);                      // wave-uniform

    if (t < 80) {
        const float4* ar = (const float4*)(A + t * 80);
        float4 s4 = {0.f, 0.f, 0.f, 0.f};
        #pragma unroll
        for (int q = 0; q < 20; q++) {
            float4 v = ar[q];
            s4.x += v.x; s4.y += v.y; s4.z += v.z; s4.w += v.w;
        }
        dinv[t] = 1.0f / sqrtf(s4.x + s4.y + s4.z + s4.w);
    }
    __syncthreads();
    ys[c0 * 8 + j] = dinv[c0] * y0g[(size_t)c0 * 1024 + j0 + j];
    ys[c1 * 8 + j] = dinv[c1] * y0g[(size_t)c1 * 1024 + j0 + j];
    if (has3) ys[c2 * 8 + j] = dinv[c2] * y0g[(size_t)c2 * 1024 + j0 + j];
    __syncthreads();

    // x1 = leaky(dinv[c] * sum_e A[e,c]*ys[e])
    float b0 = 0.f, b1 = 0.f, b2 = 0.f;
    #pragma unroll 4
    for (int e = 0; e < 80; e++) {
        float y = ys[e * 8 + j];
        b0 = fmaf(A[e * 80 + c0], y, b0);
        b1 = fmaf(A[e * 80 + c1], y, b1);
        if (has3) b2 = fmaf(A[e * 80 + c2], y, b2);
    }
    b0 *= dinv[c0];
    b1 *= dinv[c1];
    b2 *= has3 ? dinv[c2] : 0.f;
    if (b0 < 0.f) b0 *= 0.2f;
    if (b1 < 0.f) b1 *= 0.2f;
    if (b2 < 0.f) b2 *= 0.2f;
    __syncthreads();
    xs[c0 * 8 + j] = dinv[c0] * b0;
    xs[c1 * 8 + j] = dinv[c1] * b1;
    if (has3) xs[c2 * 8 + j] = dinv[c2] * b2;
    __syncthreads();

    // x2 = dinv[c] * sum_e A[e,c]*xs[e] -> bf16
    float d0 = 0.f, d1 = 0.f, d2 = 0.f;
    #pragma unroll 4
    for (int e = 0; e < 80; e++) {
        float x = xs[e * 8 + j];
        d0 = fmaf(A[e * 80 + c0], x, d0);
        d1 = fmaf(A[e * 80 + c1], x, d1);
        if (has3) d2 = fmaf(A[e * 80 + c2], x, d2);
    }
    x2b[c0 * 1024 + j0 + j] = f2bf(d0 * dinv[c0]);
    x2b[c1 * 1024 + j0 + j] = f2bf(d1 * dinv[c1]);
    if (has3) x2b[c2 * 1024 + j0 + j] = f2bf(d2 * dinv[c2]);
}

// =================== MFMA GEMMs (256 thr, BN=16, in-block 4-way K-split) ===================
template <int MF>
__device__ __forceinline__ void gemm_block(int bx, const unsigned short* __restrict__ X,
                                           const float* __restrict__ W,
                                           const float* __restrict__ bias,
                                           float* __restrict__ outf,
                                           unsigned short* __restrict__ outb,
                                           int N, int K, float (*red)[64][21]) {
    int tid = threadIdx.x;
    int ks = tid >> 6, lane = tid & 63;
    int n = bx * 16 + (lane & 15);
    int rowa = lane & 15;
    int koff = (lane >> 4) * 8;
    int Kc = K >> 2;
    int k0 = ks * Kc;

    f32x4 acc[MF];
    #pragma unroll
    for (int i = 0; i < MF; i++) acc[i] = (f32x4)(0.f);

    const float* wrow = W + (size_t)n * K;

    #pragma unroll 2
    for (int k = k0; k < k0 + Kc; k += 32) {
        float4 w0 = *(const float4*)(wrow + k + koff);
        float4 w1 = *(const float4*)(wrow + k + koff + 4);
        u16x8 bu;
        bu[0] = f2bf(w0.x); bu[1] = f2bf(w0.y); bu[2] = f2bf(w0.z); bu[3] = f2bf(w0.w);
        bu[4] = f2bf(w1.x); bu[5] = f2bf(w1.y); bu[6] = f2bf(w1.z); bu[7] = f2bf(w1.w);
        bf16x8 bf = __builtin_bit_cast(bf16x8, bu);
        #pragma unroll
        for (int mf = 0; mf < MF; mf++) {
            u16x8 au = *(const u16x8*)(X + (size_t)(mf * 16 + rowa) * K + k + koff);
            acc[mf] = __builtin_amdgcn_mfma_f32_16x16x32_bf16(
                __builtin_bit_cast(bf16x8, au), bf, acc[mf], 0, 0, 0);
        }
    }

    #pragma unroll
    for (int mf = 0; mf < MF; mf++)
        #pragma unroll
        for (int i = 0; i < 4; i++)
            red[ks][lane][mf * 4 + i] = acc[mf][i];
    __syncthreads();

    int lane2 = tid & 63, sg = tid >> 6;
    int n2 = bx * 16 + (lane2 & 15);
    float b = bias ? bias[n2] : 0.f;
    #pragma unroll
    for (int mf = 0; mf < MF; mf++) {
        int slot = mf * 4 + sg;
        float s = red[0][lane2][slot] + red[1][lane2][slot]
                + red[2][lane2][slot] + red[3][lane2][slot] + b;
        int row = mf * 16 + (lane2 >> 4) * 4 + sg;
        size_t o = (size_t)row * N + n2;
        if (outf) outf[o] = s;
        if (outb) outb[o] = f2bf(s);
    }
}

// W in [K][N] row-major: strided B loads — no transpose needed.
template <int MF>
__device__ __forceinline__ void gemm_block_kn(int bx, const unsigned short* __restrict__ X,
                                              const float* __restrict__ Wkn,
                                              const float* __restrict__ bias,
                                              float* __restrict__ outf,
                                              unsigned short* __restrict__ outb,
                                              int N, int K, float (*red)[64][21]) {
    int tid = threadIdx.x;
    int ks = tid >> 6, lane = tid & 63;
    int n = bx * 16 + (lane & 15);
    int rowa = lane & 15;
    int koff = (lane >> 4) * 8;
    int Kc = K >> 2;
    int k0 = ks * Kc;

    f32x4 acc[MF];
    #pragma unroll
    for (int i = 0; i < MF; i++) acc[i] = (f32x4)(0.f);

    #pragma unroll 2
    for (int k = k0; k < k0 + Kc; k += 32) {
        float w[8];
        #pragma unroll
        for (int i = 0; i < 8; i++) w[i] = Wkn[(size_t)(k + koff + i) * N + n];
        u16x8 bu;
        #pragma unroll
        for (int i = 0; i < 8; i++) bu[i] = f2bf(w[i]);
        bf16x8 bf = __builtin_bit_cast(bf16x8, bu);
        #pragma unroll
        for (int mf = 0; mf < MF; mf++) {
            u16x8 au = *(const u16x8*)(X + (size_t)(mf * 16 + rowa) * K + k + koff);
            acc[mf] = __builtin_amdgcn_mfma_f32_16x16x32_bf16(
                __builtin_bit_cast(bf16x8, au), bf, acc[mf], 0, 0, 0);
        }
    }

    #pragma unroll
    for (int mf = 0; mf < MF; mf++)
        #pragma unroll
        for (int i = 0; i < 4; i++)
            red[ks][lane][mf * 4 + i] = acc[mf][i];
    __syncthreads();

    int lane2 = tid & 63, sg = tid >> 6;
    int n2 = bx * 16 + (lane2 & 15);
    float b = bias ? bias[n2] : 0.f;
    #pragma unroll
    for (int mf = 0; mf < MF; mf++) {
        int slot = mf * 4 + sg;
        float s = red[0][lane2][slot] + red[1][lane2][slot]
                + red[2][lane2][slot] + red[3][lane2][slot] + b;
        int row = mf * 16 + (lane2 >> 4) * 4 + sg;
        size_t o = (size_t)row * N + n2;
        if (outf) outf[o] = s;
        if (outb) outb[o] = f2bf(s);
    }
}

// =================== kernels (6 dispatches) ===================

// A: y0 k-parallel (0-319) | maxpool (320-4415)
__global__ __launch_bounds__(256, 4) void kA(const float* __restrict__ feature,
                                             unsigned short* __restrict__ featb,
                                             const float* __restrict__ inp,
                                             const float* __restrict__ W1,
                                             float* __restrict__ y0g) {
    __shared__ __align__(16) float smem[6272];    // 25.1 KB union
    int b = blockIdx.x;
    if (b < 320) y0_role(b, inp, W1, y0g, (float4*)smem);
    else         maxpool_role(b - 320, feature, featb, (float4*)smem);
}

// B: x1x2 (0-127) | img units 0-383 (128-511)
__global__ __launch_bounds__(256, 4) void kB(const float* __restrict__ y0g,
                                             const float* __restrict__ A,
                                             unsigned short* __restrict__ x2b,
                                             const unsigned short* __restrict__ featb,
                                             const float* __restrict__ W_img,
                                             const float* __restrict__ b_img,
                                             float* __restrict__ img) {
    __shared__ __align__(16) float red[4][64][21];   // 21.5 KB
    int b = blockIdx.x;
    if (b < 128) x1x2_role(b, y0g, A, x2b, (float*)red);
    else         gemm_block<4>(b - 128, featb, W_img, b_img, img, nullptr, 8192, 2048, red);
}

// C: xb (0-127, [K][N] strided) | img units 384-511 (128-255)
__global__ __launch_bounds__(256, 4) void kC(const unsigned short* __restrict__ x2b,
                                             const float* __restrict__ W_gc2,
                                             unsigned short* __restrict__ xb,
                                             const unsigned short* __restrict__ featb,
                                             const float* __restrict__ W_img,
                                             const float* __restrict__ b_img,
                                             float* __restrict__ img) {
    __shared__ __align__(16) float red[4][64][21];
    int b = blockIdx.x;
    if (b < 128) gemm_block_kn<5>(b, x2b, W_gc2, nullptr, nullptr, xb, 2048, 1024, red);
    else         gemm_block<4>(b - 128 + 384, featb, W_img, b_img, img, nullptr, 8192, 2048, red);
}

// D: cls = xb @ W_cls^T + b_cls (512 blocks)
__global__ __launch_bounds__(256, 4) void kD(const unsigned short* __restrict__ xb,
                                             const float* __restrict__ W_cls,
                                             const float* __restrict__ b_cls,
                                             float* __restrict__ cls) {
    __shared__ __align__(16) float red[4][64][21];
    gemm_block<5>(blockIdx.x, xb, W_cls, b_cls, cls, nullptr, 8192, 2048, red);
}

// E: G[c2,j] = sum_c cls[c,j] * W_ml[c2, c*1024 + (j>>3)]; 640 blocks
__global__ __launch_bounds__(256, 4) void kE(const float* __restrict__ cls,
                                             const float* __restrict__ W_ml,
                                             float* __restrict__ G) {
    __shared__ __align__(16) float smem[8 * 80 * 16];   // 40 KB
    float (*wml)[80][16] = (float (*)[80][16])smem;
    int idx = blockIdx.x;
    int o0  = (idx & 63) * 16;
    int c2b = (idx >> 6) * 8;
    int j0  = o0 * 8;
    for (int i = threadIdx.x; i < 8 * 80 * 16; i += 256) {
        int ol = i & 15, c = (i >> 4) % 80, c2 = i / 1280;
        wml[c2][c][ol] = W_ml[(size_t)(c2b + c2) * 81920 + c * 1024 + o0 + ol];
    }
    __syncthreads();
    int jl  = threadIdx.x & 127;
    int c2h = (threadIdx.x >> 7) * 4;
    int ol  = jl >> 3;
    float acc[4] = {0.f, 0.f, 0.f, 0.f};
    for (int c = 0; c < 80; c++) {
        float cv = cls[(size_t)c * 8192 + j0 + jl];
        #pragma unroll
        for (int i = 0; i < 4; i++) acc[i] = fmaf(cv, wml[c2h + i][c][ol], acc[i]);
    }
    #pragma unroll
    for (int i = 0; i < 4; i++) G[(size_t)(c2b + c2h + i) * 8192 + j0 + jl] = acc[i];
}

// F: out[b,c2] = sum_j img[b,j]*G[c2,j] + b_ml[c2]; 640 blocks
__global__ __launch_bounds__(256, 2) void kF(const float* __restrict__ img,
                                             const float* __restrict__ G,
                                             const float* __restrict__ b_ml,
                                             float* __restrict__ out) {
    __shared__ float sm[4][8];
    int b = blockIdx.x / 10, cg = blockIdx.x % 10;
    int kc = threadIdx.x >> 6, lane = threadIdx.x & 63;
    const float* ib = img + (size_t)b * 8192 + kc * 2048;
    const float* gb = G + (size_t)(cg * 8) * 8192 + kc * 2048;
    float acc[8] = {0.f, 0.f, 0.f, 0.f, 0.f, 0.f, 0.f, 0.f};
    #pragma unroll
    for (int step = 0; step < 8; step++) {
        int k = step * 256 + lane * 4;
        float4 iv = *(const float4*)(ib + k);
        float4 gv[8];
        #pragma unroll
        for (int i = 0; i < 8; i++) gv[i] = *(const float4*)(gb + (size_t)i * 8192 + k);
        #pragma unroll
        for (int i = 0; i < 8; i++) {
            acc[i] = fmaf(iv.x, gv[i].x, acc[i]);
            acc[i] = fmaf(iv.y, gv[i].y, acc[i]);
            acc[i] = fmaf(iv.z, gv[i].z, acc[i]);
            acc[i] = fmaf(iv.w, gv[i].w, acc[i]);
        }
    }
    #pragma unroll
    for (int i = 0; i < 8; i++) {
        float v = acc[i];
        #pragma unroll
        for (int off = 32; off; off >>= 1) v += __shfl_xor(v, off);
        if (lane == 0) sm[kc][i] = v;
    }
    __syncthreads();
    if (threadIdx.x < 8) {
        int i = threadIdx.x;
        float s = b_ml[cg * 8 + i] + sm[0][i] + sm[1][i] + sm[2][i] + sm[3][i];
        out[(size_t)b * 80 + cg * 8 + i] = s;
    }
}

// ---------------- launch ----------------
extern "C" void kernel_launch(void* const* d_in, const int* in_sizes, int n_in,
                              void* d_out, int out_size, void* d_ws, size_t ws_size,
                              hipStream_t stream) {
    (void)in_sizes; (void)n_in; (void)out_size; (void)ws_size;
    const float* feature = (const float*)d_in[0];
    const float* inp     = (const float*)d_in[1];
    const float* A       = (const float*)d_in[2];
    const float* W_gc1   = (const float*)d_in[3];
    const float* W_gc2   = (const float*)d_in[4];
    const float* W_img   = (const float*)d_in[5];
    const float* b_img   = (const float*)d_in[6];
    const float* W_cls   = (const float*)d_in[7];
    const float* b_cls   = (const float*)d_in[8];
    const float* W_ml    = (const float*)d_in[9];
    const float* b_ml    = (const float*)d_in[10];
    float* out = (float*)d_out;
    char*  ws  = (char*)d_ws;

    unsigned short* featb = (unsigned short*)(ws + OFF_FEATB);
    unsigned short* x2b   = (unsigned short*)(ws + OFF_X2B);
    unsigned short* xb    = (unsigned short*)(ws + OFF_XB);
    float* img  = (float*)(ws + OFF_IMG);
    float* cls  = (float*)(ws + OFF_CLS);
    float* G    = (float*)(ws + OFF_G);
    float* y0g  = (float*)(ws + OFF_Y0);

    kA<<<4416, 256, 0, stream>>>(feature, featb, inp, W_gc1, y0g);
    kB<<<512,  256, 0, stream>>>(y0g, A, x2b, featb, W_img, b_img, img);
    kC<<<256,  256, 0, stream>>>(x2b, W_gc2, xb, featb, W_img, b_img, img);
    kD<<<512,  256, 0, stream>>>(xb, W_cls, b_cls, cls);
    kE<<<640,  256, 0, stream>>>(cls, W_ml, G);
    kF<<<640,  256, 0, stream>>>(img, G, b_ml, out);
}